// Round 1
// baseline (7597.013 us; speedup 1.0000x reference)
//
#include <hip/hip_runtime.h>
#include <math.h>

#define S_TOT 2112
#define DMODEL 768
#define NMEM 64
#define NHEAD 12
#define HDIM 64

// ---------------- embedding: x[s,:] = s<64 ? mem[s] : emb[tok[s-64]] + pos[s-64]
__global__ __launch_bounds__(256) void embed_kernel(
    const int* __restrict__ tokens, const float* __restrict__ emb,
    const float* __restrict__ pos, const float* __restrict__ mem,
    float* __restrict__ x)
{
    int s = blockIdx.x;
    int tid = threadIdx.x;
    float* xr = x + (size_t)s * DMODEL;
    if (s < NMEM) {
        const float* mr = mem + (size_t)s * DMODEL;
        for (int d = tid; d < DMODEL; d += 256) xr[d] = mr[d];
    } else {
        int t = s - NMEM;
        int tok = tokens[t];
        const float* er = emb + (size_t)tok * DMODEL;
        const float* pr = pos + (size_t)t * DMODEL;
        for (int d = tid; d < DMODEL; d += 256) xr[d] = er[d] + pr[d];
    }
}

// ---------------- layernorm: one block per row, 768 = 256*3
__global__ __launch_bounds__(256) void ln_kernel(
    const float* __restrict__ X, const float* __restrict__ g,
    const float* __restrict__ b, float* __restrict__ Y)
{
    __shared__ float red[256];
    int row = blockIdx.x, tid = threadIdx.x;
    const float* xr = X + (size_t)row * DMODEL;
    float v0 = xr[tid], v1 = xr[tid + 256], v2 = xr[tid + 512];
    red[tid] = v0 + v1 + v2;
    __syncthreads();
    for (int s = 128; s > 0; s >>= 1) {
        if (tid < s) red[tid] += red[tid + s];
        __syncthreads();
    }
    float mu = red[0] * (1.0f / 768.0f);
    __syncthreads();
    float d0 = v0 - mu, d1 = v1 - mu, d2 = v2 - mu;
    red[tid] = d0 * d0 + d1 * d1 + d2 * d2;
    __syncthreads();
    for (int s = 128; s > 0; s >>= 1) {
        if (tid < s) red[tid] += red[tid + s];
        __syncthreads();
    }
    float inv = rsqrtf(red[0] * (1.0f / 768.0f) + 1e-5f);
    float* yr = Y + (size_t)row * DMODEL;
    yr[tid]       = d0 * inv * g[tid]       + b[tid];
    yr[tid + 256] = d1 * inv * g[tid + 256] + b[tid + 256];
    yr[tid + 512] = d2 * inv * g[tid + 512] + b[tid + 512];
}

// ---------------- C[m, ncol0+n] = act(A[m,:] . B[n,:] + bias[n]) + resid[m,ncol0+n]
// A: [M,K] row-major (ld=K); B: [N,K] row-major (ld=K). 64x64 tile, 4x4/thread.
// M, N multiples of 64; K multiple of 16.
__global__ __launch_bounds__(256) void gemm_bt(
    const float* __restrict__ A, const float* __restrict__ B,
    const float* __restrict__ bias, const float* __restrict__ resid,
    float* __restrict__ C, int K, int ldc, int ncol0, int act)
{
    __shared__ float As[16][68];   // [k][m], +4 pad keeps 16B alignment, <=2-way banks
    __shared__ float Bs[16][68];   // [k][n]
    int tid = threadIdx.x;
    int tx = tid & 15, ty = tid >> 4;
    int m0 = blockIdx.y * 64, n0 = blockIdx.x * 64;
    int lr = tid >> 2;          // 0..63 tile row
    int lc = (tid & 3) << 2;    // 0,4,8,12 k-col
    const float* Ap = A + (size_t)(m0 + lr) * K + lc;
    const float* Bp = B + (size_t)(n0 + lr) * K + lc;
    float acc[4][4] = {};
    for (int k0 = 0; k0 < K; k0 += 16) {
        float4 a4 = *(const float4*)(Ap + k0);
        float4 b4 = *(const float4*)(Bp + k0);
        As[lc + 0][lr] = a4.x; As[lc + 1][lr] = a4.y;
        As[lc + 2][lr] = a4.z; As[lc + 3][lr] = a4.w;
        Bs[lc + 0][lr] = b4.x; Bs[lc + 1][lr] = b4.y;
        Bs[lc + 2][lr] = b4.z; Bs[lc + 3][lr] = b4.w;
        __syncthreads();
#pragma unroll
        for (int kk = 0; kk < 16; ++kk) {
            float4 av = *(const float4*)&As[kk][ty << 2];
            float4 bv = *(const float4*)&Bs[kk][tx << 2];
            float a[4] = {av.x, av.y, av.z, av.w};
            float bb[4] = {bv.x, bv.y, bv.z, bv.w};
#pragma unroll
            for (int i = 0; i < 4; ++i)
#pragma unroll
                for (int j = 0; j < 4; ++j)
                    acc[i][j] += a[i] * bb[j];
        }
        __syncthreads();
    }
#pragma unroll
    for (int i = 0; i < 4; ++i) {
        int m = m0 + (ty << 2) + i;
#pragma unroll
        for (int j = 0; j < 4; ++j) {
            int nn = n0 + (tx << 2) + j;
            float v = acc[i][j];
            if (bias) v += bias[nn];
            if (act) {
                float u = v;
                float t = 0.7978845608028654f * (u + 0.044715f * u * u * u);
                v = 0.5f * u * (1.0f + tanhf(t));
            }
            size_t idx = (size_t)m * ldc + ncol0 + nn;
            if (resid) v += resid[idx];
            C[idx] = v;
        }
    }
}

// ---------------- attention: one block per (query row, head). qkv: [S, 3*768].
// q at col h*64, k at 768+h*64, v at 1536+h*64. causal: keys 0..qi.
__global__ __launch_bounds__(256) void attn_kernel(
    const float* __restrict__ qkv, float* __restrict__ att)
{
    __shared__ float sc[S_TOT];
    __shared__ float qv[HDIM];
    __shared__ float red[256];
    int qi = blockIdx.x;
    int h  = blockIdx.y;
    int tid = threadIdx.x;

    const float* qrow = qkv + (size_t)qi * (3 * DMODEL) + h * HDIM;
    if (tid < HDIM) qv[tid] = qrow[tid];
    __syncthreads();

    // scores
    float lmax = -1e30f;
    for (int k = tid; k <= qi; k += 256) {
        const float* krow = qkv + (size_t)k * (3 * DMODEL) + DMODEL + h * HDIM;
        float dot = 0.0f;
#pragma unroll
        for (int d = 0; d < HDIM; d += 4) {
            float4 k4 = *(const float4*)(krow + d);
            dot += qv[d] * k4.x + qv[d + 1] * k4.y + qv[d + 2] * k4.z + qv[d + 3] * k4.w;
        }
        dot *= 0.125f;   // 1/sqrt(64)
        sc[k] = dot;
        lmax = fmaxf(lmax, dot);
    }
    red[tid] = lmax;
    __syncthreads();
    for (int s = 128; s > 0; s >>= 1) {
        if (tid < s) red[tid] = fmaxf(red[tid], red[tid + s]);
        __syncthreads();
    }
    float mx = red[0];
    __syncthreads();

    // exp + sum
    float lsum = 0.0f;
    for (int k = tid; k <= qi; k += 256) {
        float p = __expf(sc[k] - mx);
        sc[k] = p;
        lsum += p;
    }
    red[tid] = lsum;
    __syncthreads();
    for (int s = 128; s > 0; s >>= 1) {
        if (tid < s) red[tid] += red[tid + s];
        __syncthreads();
    }
    float inv = 1.0f / red[0];
    __syncthreads();

    // O = P . V ; 4 k-groups x 64 dims
    int d = tid & 63, grp = tid >> 6;
    float acc = 0.0f;
    for (int k = grp; k <= qi; k += 4)
        acc += sc[k] * qkv[(size_t)k * (3 * DMODEL) + 2 * DMODEL + h * HDIM + d];
    red[tid] = acc;
    __syncthreads();
    if (tid < 64) {
        float o = (red[tid] + red[tid + 64] + red[tid + 128] + red[tid + 192]) * inv;
        att[(size_t)qi * DMODEL + h * HDIM + d] = o;
    }
}

extern "C" void kernel_launch(void* const* d_in, const int* in_sizes, int n_in,
                              void* d_out, int out_size, void* d_ws, size_t ws_size,
                              hipStream_t stream) {
    const int*   tokens = (const int*)d_in[0];
    const float* emb    = (const float*)d_in[1];
    const float* pos    = (const float*)d_in[2];
    const float* mem    = (const float*)d_in[3];
    const float* ln1_s  = (const float*)d_in[4];
    const float* ln1_b  = (const float*)d_in[5];
    const float* wq     = (const float*)d_in[6];
    const float* wk     = (const float*)d_in[7];
    const float* wv     = (const float*)d_in[8];
    const float* wo     = (const float*)d_in[9];
    const float* ln2_s  = (const float*)d_in[10];
    const float* ln2_b  = (const float*)d_in[11];
    const float* w1     = (const float*)d_in[12];
    const float* b1     = (const float*)d_in[13];
    const float* w2     = (const float*)d_in[14];
    const float* b2     = (const float*)d_in[15];
    const float* lnm_s  = (const float*)d_in[16];
    const float* lnm_b  = (const float*)d_in[17];
    float* out = (float*)d_out;

    const int S = S_TOT, D = DMODEL, L = 4, FF = 4 * DMODEL;

    float* x    = (float*)d_ws;          // S*D
    float* nbuf = x    + (size_t)S * D;  // S*D
    float* qkvb = nbuf + (size_t)S * D;  // S*3D
    float* att  = qkvb + (size_t)S * 3 * D; // S*D
    float* ffh  = att  + (size_t)S * D;  // S*4D   (total ~65 MB)

    embed_kernel<<<S, 256, 0, stream>>>(tokens, emb, pos, mem, x);

    dim3 gD(D / 64, S / 64);     // 768-col GEMMs
    dim3 gF(FF / 64, S / 64);    // 3072-col GEMM
    dim3 gA(S, NHEAD);

    for (int l = 0; l < L; ++l) {
        ln_kernel<<<S, 256, 0, stream>>>(x, ln1_s + l * D, ln1_b + l * D, nbuf);
        gemm_bt<<<gD, 256, 0, stream>>>(nbuf, wq + (size_t)l * D * D, nullptr, nullptr,
                                        qkvb, D, 3 * D, 0, 0);
        gemm_bt<<<gD, 256, 0, stream>>>(nbuf, wk + (size_t)l * D * D, nullptr, nullptr,
                                        qkvb, D, 3 * D, D, 0);
        gemm_bt<<<gD, 256, 0, stream>>>(nbuf, wv + (size_t)l * D * D, nullptr, nullptr,
                                        qkvb, D, 3 * D, 2 * D, 0);
        attn_kernel<<<gA, 256, 0, stream>>>(qkvb, att);
        gemm_bt<<<gD, 256, 0, stream>>>(att, wo + (size_t)l * D * D, nullptr, x,
                                        x, D, D, 0, 0);
        ln_kernel<<<S, 256, 0, stream>>>(x, ln2_s + l * D, ln2_b + l * D, nbuf);
        gemm_bt<<<gF, 256, 0, stream>>>(nbuf, w1 + (size_t)l * FF * D, b1 + (size_t)l * FF,
                                        nullptr, ffh, D, FF, 0, 1);
        gemm_bt<<<gD, 256, 0, stream>>>(ffh, w2 + (size_t)l * D * FF, b2 + (size_t)l * D,
                                        x, x, FF, D, 0, 0);
    }
    ln_kernel<<<NMEM, 256, 0, stream>>>(x + (size_t)(S - NMEM) * D, lnm_s, lnm_b, out);
}

// Round 2
// 3464.433 us; speedup vs baseline: 2.1929x; 2.1929x over previous
//
#include <hip/hip_runtime.h>
#include <math.h>

#define S_TOT 2112
#define DMODEL 768
#define NMEM 64
#define NHEAD 12
#define HDIM 64

// ---------------- embedding: x[s,:] = s<64 ? mem[s] : emb[tok[s-64]] + pos[s-64]
__global__ __launch_bounds__(256) void embed_kernel(
    const int* __restrict__ tokens, const float* __restrict__ emb,
    const float* __restrict__ pos, const float* __restrict__ mem,
    float* __restrict__ x)
{
    int s = blockIdx.x;
    int tid = threadIdx.x;
    float* xr = x + (size_t)s * DMODEL;
    if (s < NMEM) {
        const float* mr = mem + (size_t)s * DMODEL;
        for (int d = tid; d < DMODEL; d += 256) xr[d] = mr[d];
    } else {
        int t = s - NMEM;
        int tok = tokens[t];
        const float* er = emb + (size_t)tok * DMODEL;
        const float* pr = pos + (size_t)t * DMODEL;
        for (int d = tid; d < DMODEL; d += 256) xr[d] = er[d] + pr[d];
    }
}

// ---------------- layernorm: one block per row, 768 = 256*3
__global__ __launch_bounds__(256) void ln_kernel(
    const float* __restrict__ X, const float* __restrict__ g,
    const float* __restrict__ b, float* __restrict__ Y)
{
    __shared__ float red[256];
    int row = blockIdx.x, tid = threadIdx.x;
    const float* xr = X + (size_t)row * DMODEL;
    float v0 = xr[tid], v1 = xr[tid + 256], v2 = xr[tid + 512];
    red[tid] = v0 + v1 + v2;
    __syncthreads();
    for (int s = 128; s > 0; s >>= 1) {
        if (tid < s) red[tid] += red[tid + s];
        __syncthreads();
    }
    float mu = red[0] * (1.0f / 768.0f);
    __syncthreads();
    float d0 = v0 - mu, d1 = v1 - mu, d2 = v2 - mu;
    red[tid] = d0 * d0 + d1 * d1 + d2 * d2;
    __syncthreads();
    for (int s = 128; s > 0; s >>= 1) {
        if (tid < s) red[tid] += red[tid + s];
        __syncthreads();
    }
    float inv = rsqrtf(red[0] * (1.0f / 768.0f) + 1e-5f);
    float* yr = Y + (size_t)row * DMODEL;
    yr[tid]       = d0 * inv * g[tid]       + b[tid];
    yr[tid + 256] = d1 * inv * g[tid + 256] + b[tid + 256];
    yr[tid + 512] = d2 * inv * g[tid + 512] + b[tid + 512];
}

// ---------------- C[m, ncol0+n] = act(A[m,:] . B[n,:] + bias[n]) + resid[m,ncol0+n]
__global__ __launch_bounds__(256) void gemm_bt(
    const float* __restrict__ A, const float* __restrict__ B,
    const float* __restrict__ bias, const float* __restrict__ resid,
    float* __restrict__ C, int K, int ldc, int ncol0, int act)
{
    __shared__ float As[16][68];
    __shared__ float Bs[16][68];
    int tid = threadIdx.x;
    int tx = tid & 15, ty = tid >> 4;
    int m0 = blockIdx.y * 64, n0 = blockIdx.x * 64;
    int lr = tid >> 2;
    int lc = (tid & 3) << 2;
    const float* Ap = A + (size_t)(m0 + lr) * K + lc;
    const float* Bp = B + (size_t)(n0 + lr) * K + lc;
    float acc[4][4] = {};
    for (int k0 = 0; k0 < K; k0 += 16) {
        float4 a4 = *(const float4*)(Ap + k0);
        float4 b4 = *(const float4*)(Bp + k0);
        As[lc + 0][lr] = a4.x; As[lc + 1][lr] = a4.y;
        As[lc + 2][lr] = a4.z; As[lc + 3][lr] = a4.w;
        Bs[lc + 0][lr] = b4.x; Bs[lc + 1][lr] = b4.y;
        Bs[lc + 2][lr] = b4.z; Bs[lc + 3][lr] = b4.w;
        __syncthreads();
#pragma unroll
        for (int kk = 0; kk < 16; ++kk) {
            float4 av = *(const float4*)&As[kk][ty << 2];
            float4 bv = *(const float4*)&Bs[kk][tx << 2];
            float a[4] = {av.x, av.y, av.z, av.w};
            float bb[4] = {bv.x, bv.y, bv.z, bv.w};
#pragma unroll
            for (int i = 0; i < 4; ++i)
#pragma unroll
                for (int j = 0; j < 4; ++j)
                    acc[i][j] += a[i] * bb[j];
        }
        __syncthreads();
    }
#pragma unroll
    for (int i = 0; i < 4; ++i) {
        int m = m0 + (ty << 2) + i;
#pragma unroll
        for (int j = 0; j < 4; ++j) {
            int nn = n0 + (tx << 2) + j;
            float v = acc[i][j];
            if (bias) v += bias[nn];
            if (act) {
                float u = v;
                float t = 0.7978845608028654f * (u + 0.044715f * u * u * u);
                v = 0.5f * u * (1.0f + tanhf(t));
            }
            size_t idx = (size_t)m * ldc + ncol0 + nn;
            if (resid) v += resid[idx];
            C[idx] = v;
        }
    }
}

// ---------------- flash attention: block = (q-tile of 64, head). 256 thr, 4x4 microtile.
// qkv: [S, 2304]; q at h*64, k at 768+h*64, v at 1536+h*64. att: [S, 768].
__global__ __launch_bounds__(256) void attn_flash(
    const float* __restrict__ qkv, float* __restrict__ att)
{
    __shared__ float Qs[64][68];   // [d][i]  k-major for QK^T
    __shared__ float Ks[64][68];   // [d][j]
    __shared__ float Vs[64][68];   // [j][d]  natural for PV
    __shared__ float Ps[64][68];   // [j][i]  k-major for PV
    __shared__ float redm[64][17];
    __shared__ float reds[64][17];
    __shared__ float mstate[64];
    __shared__ float lstate[64];
    __shared__ float alpha_s[64];

    int qt  = (int)gridDim.x - 1 - (int)blockIdx.x;  // heavy tiles dispatched first
    int h   = blockIdx.y;
    int tid = threadIdx.x;
    int tx = tid & 15, ty = tid >> 4;
    int lr = tid >> 2;           // 0..63 row for staging
    int lc = (tid & 3) << 4;     // 0,16,32,48 col group for staging

    // stage Q tile transposed: Qs[d][i]
    {
        const float* qrow = qkv + (size_t)(qt * 64 + lr) * (3 * DMODEL) + h * HDIM + lc;
#pragma unroll
        for (int k4 = 0; k4 < 16; k4 += 4) {
            float4 v = *(const float4*)(qrow + k4);
            Qs[lc + k4 + 0][lr] = v.x; Qs[lc + k4 + 1][lr] = v.y;
            Qs[lc + k4 + 2][lr] = v.z; Qs[lc + k4 + 3][lr] = v.w;
        }
    }
    if (tid < 64) { mstate[tid] = -1e30f; lstate[tid] = 0.0f; }

    float accO[4][4] = {};

    for (int kt = 0; kt <= qt; ++kt) {
        __syncthreads();   // protect Ks/Vs/Ps from previous iteration's readers
        // stage K (transposed) and V (natural)
        {
            const float* krow = qkv + (size_t)(kt * 64 + lr) * (3 * DMODEL) + DMODEL + h * HDIM + lc;
            const float* vrow = qkv + (size_t)(kt * 64 + lr) * (3 * DMODEL) + 2 * DMODEL + h * HDIM + lc;
#pragma unroll
            for (int k4 = 0; k4 < 16; k4 += 4) {
                float4 kv = *(const float4*)(krow + k4);
                Ks[lc + k4 + 0][lr] = kv.x; Ks[lc + k4 + 1][lr] = kv.y;
                Ks[lc + k4 + 2][lr] = kv.z; Ks[lc + k4 + 3][lr] = kv.w;
                *(float4*)&Vs[lr][lc + k4] = *(const float4*)(vrow + k4);
            }
        }
        __syncthreads();

        // S = Q K^T (64x64x64)
        float acc[4][4] = {};
#pragma unroll 16
        for (int kk = 0; kk < 64; ++kk) {
            float4 av = *(const float4*)&Qs[kk][ty << 2];
            float4 bv = *(const float4*)&Ks[kk][tx << 2];
            float a[4] = {av.x, av.y, av.z, av.w};
            float b[4] = {bv.x, bv.y, bv.z, bv.w};
#pragma unroll
            for (int i = 0; i < 4; ++i)
#pragma unroll
                for (int j = 0; j < 4; ++j)
                    acc[i][j] += a[i] * b[j];
        }

        // scale + causal mask (diagonal tile) + per-row partial max
        bool diag = (kt == qt);
#pragma unroll
        for (int i = 0; i < 4; ++i) {
            float rmax = -1e30f;
#pragma unroll
            for (int j = 0; j < 4; ++j) {
                float s = acc[i][j] * 0.125f;
                if (diag && ((tx << 2) + j) > ((ty << 2) + i)) s = -1e30f;
                acc[i][j] = s;
                rmax = fmaxf(rmax, s);
            }
            redm[(ty << 2) + i][tx] = rmax;
        }
        __syncthreads();
        if (tid < 64) {
            float m = redm[tid][0];
#pragma unroll
            for (int c = 1; c < 16; ++c) m = fmaxf(m, redm[tid][c]);
            float mold = mstate[tid];
            float mnew = fmaxf(mold, m);
            mstate[tid] = mnew;
            alpha_s[tid] = __expf(mold - mnew);
        }
        __syncthreads();

        // P = exp(S - m) -> Ps[j][i]; partial row sums
#pragma unroll
        for (int i = 0; i < 4; ++i) {
            float m = mstate[(ty << 2) + i];
            float rsum = 0.0f;
#pragma unroll
            for (int j = 0; j < 4; ++j) {
                float p = __expf(acc[i][j] - m);
                rsum += p;
                Ps[(tx << 2) + j][(ty << 2) + i] = p;
            }
            reds[(ty << 2) + i][tx] = rsum;
        }
        __syncthreads();
        if (tid < 64) {
            float s = 0.0f;
#pragma unroll
            for (int c = 0; c < 16; ++c) s += reds[tid][c];
            lstate[tid] = lstate[tid] * alpha_s[tid] + s;
        }
        // rescale O by alpha (alpha_s stable until 2 syncs into next iter)
#pragma unroll
        for (int i = 0; i < 4; ++i) {
            float a = alpha_s[(ty << 2) + i];
#pragma unroll
            for (int j = 0; j < 4; ++j) accO[i][j] *= a;
        }
        // O += P V (64x64x64)
#pragma unroll 16
        for (int kk = 0; kk < 64; ++kk) {
            float4 av = *(const float4*)&Ps[kk][ty << 2];
            float4 bv = *(const float4*)&Vs[kk][tx << 2];
            float a[4] = {av.x, av.y, av.z, av.w};
            float b[4] = {bv.x, bv.y, bv.z, bv.w};
#pragma unroll
            for (int i = 0; i < 4; ++i)
#pragma unroll
                for (int j = 0; j < 4; ++j)
                    accO[i][j] += a[i] * b[j];
        }
    }
    __syncthreads();
#pragma unroll
    for (int i = 0; i < 4; ++i) {
        int row = (ty << 2) + i;
        float inv = 1.0f / lstate[row];
        float4 o;
        o.x = accO[i][0] * inv; o.y = accO[i][1] * inv;
        o.z = accO[i][2] * inv; o.w = accO[i][3] * inv;
        *(float4*)(att + (size_t)(qt * 64 + row) * DMODEL + h * HDIM + (tx << 2)) = o;
    }
}

extern "C" void kernel_launch(void* const* d_in, const int* in_sizes, int n_in,
                              void* d_out, int out_size, void* d_ws, size_t ws_size,
                              hipStream_t stream) {
    const int*   tokens = (const int*)d_in[0];
    const float* emb    = (const float*)d_in[1];
    const float* pos    = (const float*)d_in[2];
    const float* mem    = (const float*)d_in[3];
    const float* ln1_s  = (const float*)d_in[4];
    const float* ln1_b  = (const float*)d_in[5];
    const float* wq     = (const float*)d_in[6];
    const float* wk     = (const float*)d_in[7];
    const float* wv     = (const float*)d_in[8];
    const float* wo     = (const float*)d_in[9];
    const float* ln2_s  = (const float*)d_in[10];
    const float* ln2_b  = (const float*)d_in[11];
    const float* w1     = (const float*)d_in[12];
    const float* b1     = (const float*)d_in[13];
    const float* w2     = (const float*)d_in[14];
    const float* b2     = (const float*)d_in[15];
    const float* lnm_s  = (const float*)d_in[16];
    const float* lnm_b  = (const float*)d_in[17];
    float* out = (float*)d_out;

    const int S = S_TOT, D = DMODEL, L = 4, FF = 4 * DMODEL;

    float* x    = (float*)d_ws;             // S*D
    float* nbuf = x    + (size_t)S * D;     // S*D
    float* qkvb = nbuf + (size_t)S * D;     // S*3D
    float* att  = qkvb + (size_t)S * 3 * D; // S*D
    float* ffh  = att  + (size_t)S * D;     // S*4D

    embed_kernel<<<S, 256, 0, stream>>>(tokens, emb, pos, mem, x);

    dim3 gD(D / 64, S / 64);
    dim3 gF(FF / 64, S / 64);
    dim3 gA(S / 64, NHEAD);

    for (int l = 0; l < L; ++l) {
        ln_kernel<<<S, 256, 0, stream>>>(x, ln1_s + l * D, ln1_b + l * D, nbuf);
        gemm_bt<<<gD, 256, 0, stream>>>(nbuf, wq + (size_t)l * D * D, nullptr, nullptr,
                                        qkvb, D, 3 * D, 0, 0);
        gemm_bt<<<gD, 256, 0, stream>>>(nbuf, wk + (size_t)l * D * D, nullptr, nullptr,
                                        qkvb, D, 3 * D, D, 0);
        gemm_bt<<<gD, 256, 0, stream>>>(nbuf, wv + (size_t)l * D * D, nullptr, nullptr,
                                        qkvb, D, 3 * D, 2 * D, 0);
        attn_flash<<<gA, 256, 0, stream>>>(qkvb, att);
        gemm_bt<<<gD, 256, 0, stream>>>(att, wo + (size_t)l * D * D, nullptr, x,
                                        x, D, D, 0, 0);
        ln_kernel<<<S, 256, 0, stream>>>(x, ln2_s + l * D, ln2_b + l * D, nbuf);
        gemm_bt<<<gF, 256, 0, stream>>>(nbuf, w1 + (size_t)l * FF * D, b1 + (size_t)l * FF,
                                        nullptr, ffh, D, FF, 0, 1);
        gemm_bt<<<gD, 256, 0, stream>>>(ffh, w2 + (size_t)l * D * FF, b2 + (size_t)l * D,
                                        x, x, FF, D, 0, 0);
    }
    ln_kernel<<<NMEM, 256, 0, stream>>>(x + (size_t)(S - NMEM) * D, lnm_s, lnm_b, out);
}

// Round 3
// 2124.422 us; speedup vs baseline: 3.5760x; 1.6308x over previous
//
#include <hip/hip_runtime.h>
#include <math.h>

#define S_TOT 2112
#define SPAD  2176   // 17 * 128
#define DMODEL 768
#define NMEM 64
#define NHEAD 12
#define HDIM 64

typedef unsigned short ushort_t;
typedef __attribute__((ext_vector_type(8))) short short8;
typedef __attribute__((ext_vector_type(4))) float f32x4;

__device__ __forceinline__ ushort_t f2bf(float f) {
    unsigned int u = __builtin_bit_cast(unsigned int, f);
    u = (u + 0x7FFFu + ((u >> 16) & 1u)) >> 16;   // RNE
    return (ushort_t)u;
}

#define GLD_LDS16(gp, lp) \
    __builtin_amdgcn_global_load_lds((const __attribute__((address_space(1))) void*)(gp), \
                                     (__attribute__((address_space(3))) void*)(lp), 16, 0, 0)

// ---------------- f32 -> bf16 convert (grid-stride x4)
__global__ __launch_bounds__(256) void cvt_kernel(
    const float* __restrict__ src, ushort_t* __restrict__ dst, int n)
{
    int i = (blockIdx.x * 256 + threadIdx.x) * 4;
    if (i < n) {
        float4 v = *(const float4*)(src + i);
        ushort4 o;
        o.x = f2bf(v.x); o.y = f2bf(v.y); o.z = f2bf(v.z); o.w = f2bf(v.w);
        *(ushort4*)(dst + i) = o;
    }
}

// ---------------- embedding (pads rows >= S_TOT with zeros)
__global__ __launch_bounds__(256) void embed_kernel(
    const int* __restrict__ tokens, const float* __restrict__ emb,
    const float* __restrict__ pos, const float* __restrict__ mem,
    float* __restrict__ x)
{
    int s = blockIdx.x;
    int tid = threadIdx.x;
    float* xr = x + (size_t)s * DMODEL;
    if (s >= S_TOT) {
        for (int d = tid; d < DMODEL; d += 256) xr[d] = 0.0f;
    } else if (s < NMEM) {
        const float* mr = mem + (size_t)s * DMODEL;
        for (int d = tid; d < DMODEL; d += 256) xr[d] = mr[d];
    } else {
        int t = s - NMEM;
        int tok = tokens[t];
        const float* er = emb + (size_t)tok * DMODEL;
        const float* pr = pos + (size_t)t * DMODEL;
        for (int d = tid; d < DMODEL; d += 256) xr[d] = er[d] + pr[d];
    }
}

// ---------------- layernorm: one block per row; OUT = float or ushort_t(bf16)
template <typename OUT>
__global__ __launch_bounds__(256) void ln_kernel(
    const float* __restrict__ X, const float* __restrict__ g,
    const float* __restrict__ b, OUT* __restrict__ Y)
{
    __shared__ float red[256];
    int row = blockIdx.x, tid = threadIdx.x;
    const float* xr = X + (size_t)row * DMODEL;
    float v0 = xr[tid], v1 = xr[tid + 256], v2 = xr[tid + 512];
    red[tid] = v0 + v1 + v2;
    __syncthreads();
    for (int s = 128; s > 0; s >>= 1) {
        if (tid < s) red[tid] += red[tid + s];
        __syncthreads();
    }
    float mu = red[0] * (1.0f / 768.0f);
    __syncthreads();
    float d0 = v0 - mu, d1 = v1 - mu, d2 = v2 - mu;
    red[tid] = d0 * d0 + d1 * d1 + d2 * d2;
    __syncthreads();
    for (int s = 128; s > 0; s >>= 1) {
        if (tid < s) red[tid] += red[tid + s];
        __syncthreads();
    }
    float inv = rsqrtf(red[0] * (1.0f / 768.0f) + 1e-5f);
    OUT* yr = Y + (size_t)row * DMODEL;
    float o0 = d0 * inv * g[tid]       + b[tid];
    float o1 = d1 * inv * g[tid + 256] + b[tid + 256];
    float o2 = d2 * inv * g[tid + 512] + b[tid + 512];
    if constexpr (sizeof(OUT) == 2) {
        yr[tid] = f2bf(o0); yr[tid + 256] = f2bf(o1); yr[tid + 512] = f2bf(o2);
    } else {
        yr[tid] = o0; yr[tid + 256] = o1; yr[tid + 512] = o2;
    }
}

// ---------------- bf16 MFMA GEMM (m97 structure): C = act(A.B^T + bias) (+resid)
// A: [M, K] bf16 row-major (M = 17*128 padded), B: [N, K] bf16 row-major.
// 128x128 tile, BK=32, 4 waves 2x2, 16x16x32 MFMA, global_load_lds w=16,
// XOR-swizzled LDS (2-way bank aliasing on frag reads = free).
__global__ __launch_bounds__(256) void gemm_mfma(
    const ushort_t* __restrict__ A, const ushort_t* __restrict__ B,
    const float* __restrict__ bias, const float* __restrict__ resid,
    void* __restrict__ Cp, int K, int ldc, int ncol0, int act, int c_bf16)
{
    __shared__ ushort_t As[4096];   // 128 rows x 32 cols, 64 B/row, swizzled
    __shared__ ushort_t Bs[4096];
    int tid = threadIdx.x;
    int l = tid & 63, w = tid >> 6;
    int wr = w >> 1, wc = w & 1;
    int m0 = blockIdx.y * 128, n0 = blockIdx.x * 128;

    // staging coords: issue it covers LDS bytes [w*1024 + it*4096, +1024)
    int srow[2], scol[2];
#pragma unroll
    for (int it = 0; it < 2; ++it) {
        int o = w * 1024 + it * 4096 + l * 16;
        int row = o >> 6;
        int sw = (o >> 4) & 3;
        srow[it] = row;
        scol[it] = (sw ^ ((row >> 1) & 3)) * 8;
    }
    const ushort_t* Abase = A + (size_t)m0 * K;
    const ushort_t* Bbase = B + (size_t)n0 * K;

    // fragment LDS byte offsets
    int kc = l >> 4, mr = l & 15;
    int aoff[4], boff[4];
#pragma unroll
    for (int i = 0; i < 4; ++i) {
        int r = wr * 64 + i * 16 + mr;
        aoff[i] = r * 64 + ((kc ^ ((r >> 1) & 3)) << 4);
        r = wc * 64 + i * 16 + mr;
        boff[i] = r * 64 + ((kc ^ ((r >> 1) & 3)) << 4);
    }

    f32x4 acc[4][4];
#pragma unroll
    for (int i = 0; i < 4; ++i)
#pragma unroll
        for (int j = 0; j < 4; ++j)
            acc[i][j] = (f32x4){0.f, 0.f, 0.f, 0.f};

    for (int k0 = 0; k0 < K; k0 += 32) {
        __syncthreads();
#pragma unroll
        for (int it = 0; it < 2; ++it) {
            GLD_LDS16(Abase + (size_t)srow[it] * K + k0 + scol[it],
                      (char*)As + w * 1024 + it * 4096);
            GLD_LDS16(Bbase + (size_t)srow[it] * K + k0 + scol[it],
                      (char*)Bs + w * 1024 + it * 4096);
        }
        __syncthreads();
        short8 af[4], bfr[4];
#pragma unroll
        for (int i = 0; i < 4; ++i) {
            af[i]  = *(const short8*)((const char*)As + aoff[i]);
            bfr[i] = *(const short8*)((const char*)Bs + boff[i]);
        }
#pragma unroll
        for (int i = 0; i < 4; ++i)
#pragma unroll
            for (int j = 0; j < 4; ++j)
                acc[i][j] = __builtin_amdgcn_mfma_f32_16x16x32_bf16(af[i], bfr[j], acc[i][j], 0, 0, 0);
    }

    // epilogue: D row = (l>>4)*4 + reg, col = l&15 (m89-verified)
    int lq = l >> 4;
#pragma unroll
    for (int i = 0; i < 4; ++i) {
#pragma unroll
        for (int r = 0; r < 4; ++r) {
            int m = m0 + wr * 64 + i * 16 + lq * 4 + r;
#pragma unroll
            for (int j = 0; j < 4; ++j) {
                int n = n0 + wc * 64 + j * 16 + mr;
                float v = acc[i][j][r];
                if (bias) v += bias[n];
                if (act) {
                    float u = v;
                    float t = 0.7978845608028654f * (u + 0.044715f * u * u * u);
                    v = 0.5f * u * (1.0f + tanhf(t));
                }
                size_t idx = (size_t)m * ldc + ncol0 + n;
                if (resid) v += resid[idx];
                if (c_bf16) ((ushort_t*)Cp)[idx] = f2bf(v);
                else        ((float*)Cp)[idx] = v;
            }
        }
    }
}

// ---------------- flash attention (f32 compute), bf16 output
__global__ __launch_bounds__(256) void attn_flash(
    const float* __restrict__ qkv, ushort_t* __restrict__ att)
{
    __shared__ float Qs[64][68];
    __shared__ float Ks[64][68];
    __shared__ float Vs[64][68];
    __shared__ float Ps[64][68];
    __shared__ float redm[64][17];
    __shared__ float reds[64][17];
    __shared__ float mstate[64];
    __shared__ float lstate[64];
    __shared__ float alpha_s[64];

    int qt  = (int)gridDim.x - 1 - (int)blockIdx.x;
    int h   = blockIdx.y;
    int tid = threadIdx.x;
    int tx = tid & 15, ty = tid >> 4;
    int lr = tid >> 2;
    int lc = (tid & 3) << 4;

    {
        const float* qrow = qkv + (size_t)(qt * 64 + lr) * (3 * DMODEL) + h * HDIM + lc;
#pragma unroll
        for (int k4 = 0; k4 < 16; k4 += 4) {
            float4 v = *(const float4*)(qrow + k4);
            Qs[lc + k4 + 0][lr] = v.x; Qs[lc + k4 + 1][lr] = v.y;
            Qs[lc + k4 + 2][lr] = v.z; Qs[lc + k4 + 3][lr] = v.w;
        }
    }
    if (tid < 64) { mstate[tid] = -1e30f; lstate[tid] = 0.0f; }

    float accO[4][4] = {};

    for (int kt = 0; kt <= qt; ++kt) {
        __syncthreads();
        {
            const float* krow = qkv + (size_t)(kt * 64 + lr) * (3 * DMODEL) + DMODEL + h * HDIM + lc;
            const float* vrow = qkv + (size_t)(kt * 64 + lr) * (3 * DMODEL) + 2 * DMODEL + h * HDIM + lc;
#pragma unroll
            for (int k4 = 0; k4 < 16; k4 += 4) {
                float4 kv = *(const float4*)(krow + k4);
                Ks[lc + k4 + 0][lr] = kv.x; Ks[lc + k4 + 1][lr] = kv.y;
                Ks[lc + k4 + 2][lr] = kv.z; Ks[lc + k4 + 3][lr] = kv.w;
                *(float4*)&Vs[lr][lc + k4] = *(const float4*)(vrow + k4);
            }
        }
        __syncthreads();

        float acc[4][4] = {};
#pragma unroll 16
        for (int kk = 0; kk < 64; ++kk) {
            float4 av = *(const float4*)&Qs[kk][ty << 2];
            float4 bv = *(const float4*)&Ks[kk][tx << 2];
            float a[4] = {av.x, av.y, av.z, av.w};
            float b[4] = {bv.x, bv.y, bv.z, bv.w};
#pragma unroll
            for (int i = 0; i < 4; ++i)
#pragma unroll
                for (int j = 0; j < 4; ++j)
                    acc[i][j] += a[i] * b[j];
        }

        bool diag = (kt == qt);
#pragma unroll
        for (int i = 0; i < 4; ++i) {
            float rmax = -1e30f;
#pragma unroll
            for (int j = 0; j < 4; ++j) {
                float s = acc[i][j] * 0.125f;
                if (diag && ((tx << 2) + j) > ((ty << 2) + i)) s = -1e30f;
                acc[i][j] = s;
                rmax = fmaxf(rmax, s);
            }
            redm[(ty << 2) + i][tx] = rmax;
        }
        __syncthreads();
        if (tid < 64) {
            float m = redm[tid][0];
#pragma unroll
            for (int c = 1; c < 16; ++c) m = fmaxf(m, redm[tid][c]);
            float mold = mstate[tid];
            float mnew = fmaxf(mold, m);
            mstate[tid] = mnew;
            alpha_s[tid] = __expf(mold - mnew);
        }
        __syncthreads();

#pragma unroll
        for (int i = 0; i < 4; ++i) {
            float m = mstate[(ty << 2) + i];
            float rsum = 0.0f;
#pragma unroll
            for (int j = 0; j < 4; ++j) {
                float p = __expf(acc[i][j] - m);
                rsum += p;
                Ps[(tx << 2) + j][(ty << 2) + i] = p;
            }
            reds[(ty << 2) + i][tx] = rsum;
        }
        __syncthreads();
        if (tid < 64) {
            float s = 0.0f;
#pragma unroll
            for (int c = 0; c < 16; ++c) s += reds[tid][c];
            lstate[tid] = lstate[tid] * alpha_s[tid] + s;
        }
#pragma unroll
        for (int i = 0; i < 4; ++i) {
            float a = alpha_s[(ty << 2) + i];
#pragma unroll
            for (int j = 0; j < 4; ++j) accO[i][j] *= a;
        }
#pragma unroll 16
        for (int kk = 0; kk < 64; ++kk) {
            float4 av = *(const float4*)&Ps[kk][ty << 2];
            float4 bv = *(const float4*)&Vs[kk][tx << 2];
            float a[4] = {av.x, av.y, av.z, av.w};
            float b[4] = {bv.x, bv.y, bv.z, bv.w};
#pragma unroll
            for (int i = 0; i < 4; ++i)
#pragma unroll
                for (int j = 0; j < 4; ++j)
                    accO[i][j] += a[i] * b[j];
        }
    }
    __syncthreads();
#pragma unroll
    for (int i = 0; i < 4; ++i) {
        int row = (ty << 2) + i;
        float inv = 1.0f / lstate[row];
        ushort_t* dst = att + (size_t)(qt * 64 + row) * DMODEL + h * HDIM + (tx << 2);
        dst[0] = f2bf(accO[i][0] * inv);
        dst[1] = f2bf(accO[i][1] * inv);
        dst[2] = f2bf(accO[i][2] * inv);
        dst[3] = f2bf(accO[i][3] * inv);
    }
}

extern "C" void kernel_launch(void* const* d_in, const int* in_sizes, int n_in,
                              void* d_out, int out_size, void* d_ws, size_t ws_size,
                              hipStream_t stream) {
    const int*   tokens = (const int*)d_in[0];
    const float* emb    = (const float*)d_in[1];
    const float* pos    = (const float*)d_in[2];
    const float* mem    = (const float*)d_in[3];
    const float* ln1_s  = (const float*)d_in[4];
    const float* ln1_b  = (const float*)d_in[5];
    const float* wq     = (const float*)d_in[6];
    const float* wk     = (const float*)d_in[7];
    const float* wv     = (const float*)d_in[8];
    const float* wo     = (const float*)d_in[9];
    const float* ln2_s  = (const float*)d_in[10];
    const float* ln2_b  = (const float*)d_in[11];
    const float* w1     = (const float*)d_in[12];
    const float* b1     = (const float*)d_in[13];
    const float* w2     = (const float*)d_in[14];
    const float* b2     = (const float*)d_in[15];
    const float* lnm_s  = (const float*)d_in[16];
    const float* lnm_b  = (const float*)d_in[17];
    float* out = (float*)d_out;

    const int D = DMODEL, L = 4, FF = 4 * DMODEL, SP = SPAD;
    const int DD = D * D;            // 589824
    const int DF = D * FF;           // 2359296

    float*    x    = (float*)d_ws;                       // SP*768 f32
    float*    qkvb = x + (size_t)SP * D;                 // SP*2304 f32
    ushort_t* nbuf = (ushort_t*)(qkvb + (size_t)SP * 3 * D); // SP*768 bf16
    ushort_t* attb = nbuf + (size_t)SP * D;              // SP*768 bf16
    ushort_t* ffh  = attb + (size_t)SP * D;              // SP*3072 bf16
    ushort_t* wqkv = ffh  + (size_t)SP * FF;             // 2304*768 bf16
    ushort_t* wob  = wqkv + (size_t)3 * DD;              // 768*768
    ushort_t* w1b  = wob  + (size_t)DD;                  // 3072*768
    ushort_t* w2b  = w1b  + (size_t)DF;                  // 768*3072

    embed_kernel<<<SP, 256, 0, stream>>>(tokens, emb, pos, mem, x);

    dim3 gQKV(18, 17);   // N=2304
    dim3 gO(6, 17);      // N=768
    dim3 gF1(24, 17);    // N=3072
    dim3 gA(S_TOT / 64, NHEAD);

    for (int l = 0; l < L; ++l) {
        cvt_kernel<<<DD / 1024, 256, 0, stream>>>(wq + (size_t)l * DD, wqkv, DD);
        cvt_kernel<<<DD / 1024, 256, 0, stream>>>(wk + (size_t)l * DD, wqkv + DD, DD);
        cvt_kernel<<<DD / 1024, 256, 0, stream>>>(wv + (size_t)l * DD, wqkv + 2 * DD, DD);
        cvt_kernel<<<DD / 1024, 256, 0, stream>>>(wo + (size_t)l * DD, wob, DD);
        cvt_kernel<<<DF / 1024, 256, 0, stream>>>(w1 + (size_t)l * DF, w1b, DF);
        cvt_kernel<<<DF / 1024, 256, 0, stream>>>(w2 + (size_t)l * DF, w2b, DF);

        ln_kernel<ushort_t><<<SP, 256, 0, stream>>>(x, ln1_s + l * D, ln1_b + l * D, nbuf);
        gemm_mfma<<<gQKV, 256, 0, stream>>>(nbuf, wqkv, nullptr, nullptr,
                                            qkvb, D, 3 * D, 0, 0, 0);
        attn_flash<<<gA, 256, 0, stream>>>(qkvb, attb);
        gemm_mfma<<<gO, 256, 0, stream>>>(attb, wob, nullptr, x,
                                          x, D, D, 0, 0, 0);
        ln_kernel<ushort_t><<<SP, 256, 0, stream>>>(x, ln2_s + l * D, ln2_b + l * D, nbuf);
        gemm_mfma<<<gF1, 256, 0, stream>>>(nbuf, w1b, b1 + (size_t)l * FF, nullptr,
                                           ffh, D, FF, 0, 1, 1);
        gemm_mfma<<<gO, 256, 0, stream>>>(ffh, w2b, b2 + (size_t)l * D, x,
                                          x, FF, D, 0, 0, 0);
    }
    ln_kernel<float><<<NMEM, 256, 0, stream>>>(x + (size_t)(S_TOT - NMEM) * D,
                                               lnm_s, lnm_b, out);
}

// Round 4
// 1445.607 us; speedup vs baseline: 5.2552x; 1.4696x over previous
//
#include <hip/hip_runtime.h>
#include <math.h>

#define S_TOT 2112
#define SPAD  2176   // 17 * 128
#define DMODEL 768
#define QKVLD 2304
#define NMEM 64
#define NHEAD 12
#define HDIM 64

typedef unsigned short ushort_t;
typedef __attribute__((ext_vector_type(8))) short short8;
typedef __attribute__((ext_vector_type(4))) float f32x4;

__device__ __forceinline__ ushort_t f2bf(float f) {
    unsigned int u = __builtin_bit_cast(unsigned int, f);
    u = (u + 0x7FFFu + ((u >> 16) & 1u)) >> 16;   // RNE
    return (ushort_t)u;
}

#define GLD_LDS16(gp, lp) \
    __builtin_amdgcn_global_load_lds((const __attribute__((address_space(1))) void*)(gp), \
                                     (__attribute__((address_space(3))) void*)(lp), 16, 0, 0)

// ---------------- f32 -> bf16 convert
__global__ __launch_bounds__(256) void cvt_kernel(
    const float* __restrict__ src, ushort_t* __restrict__ dst, int n)
{
    int i = (blockIdx.x * 256 + threadIdx.x) * 4;
    if (i < n) {
        float4 v = *(const float4*)(src + i);
        ushort4 o;
        o.x = f2bf(v.x); o.y = f2bf(v.y); o.z = f2bf(v.z); o.w = f2bf(v.w);
        *(ushort4*)(dst + i) = o;
    }
}

// ---------------- embedding (pads rows >= S_TOT with zeros)
__global__ __launch_bounds__(256) void embed_kernel(
    const int* __restrict__ tokens, const float* __restrict__ emb,
    const float* __restrict__ pos, const float* __restrict__ mem,
    float* __restrict__ x)
{
    int s = blockIdx.x;
    int tid = threadIdx.x;
    float* xr = x + (size_t)s * DMODEL;
    if (s >= S_TOT) {
        for (int d = tid; d < DMODEL; d += 256) xr[d] = 0.0f;
    } else if (s < NMEM) {
        const float* mr = mem + (size_t)s * DMODEL;
        for (int d = tid; d < DMODEL; d += 256) xr[d] = mr[d];
    } else {
        int t = s - NMEM;
        int tok = tokens[t];
        const float* er = emb + (size_t)tok * DMODEL;
        const float* pr = pos + (size_t)t * DMODEL;
        for (int d = tid; d < DMODEL; d += 256) xr[d] = er[d] + pr[d];
    }
}

// ---------------- layernorm
template <typename OUT>
__global__ __launch_bounds__(256) void ln_kernel(
    const float* __restrict__ X, const float* __restrict__ g,
    const float* __restrict__ b, OUT* __restrict__ Y)
{
    __shared__ float red[256];
    int row = blockIdx.x, tid = threadIdx.x;
    const float* xr = X + (size_t)row * DMODEL;
    float v0 = xr[tid], v1 = xr[tid + 256], v2 = xr[tid + 512];
    red[tid] = v0 + v1 + v2;
    __syncthreads();
    for (int s = 128; s > 0; s >>= 1) {
        if (tid < s) red[tid] += red[tid + s];
        __syncthreads();
    }
    float mu = red[0] * (1.0f / 768.0f);
    __syncthreads();
    float d0 = v0 - mu, d1 = v1 - mu, d2 = v2 - mu;
    red[tid] = d0 * d0 + d1 * d1 + d2 * d2;
    __syncthreads();
    for (int s = 128; s > 0; s >>= 1) {
        if (tid < s) red[tid] += red[tid + s];
        __syncthreads();
    }
    float inv = rsqrtf(red[0] * (1.0f / 768.0f) + 1e-5f);
    OUT* yr = Y + (size_t)row * DMODEL;
    float o0 = d0 * inv * g[tid]       + b[tid];
    float o1 = d1 * inv * g[tid + 256] + b[tid + 256];
    float o2 = d2 * inv * g[tid + 512] + b[tid + 512];
    if constexpr (sizeof(OUT) == 2) {
        yr[tid] = f2bf(o0); yr[tid + 256] = f2bf(o1); yr[tid + 512] = f2bf(o2);
    } else {
        yr[tid] = o0; yr[tid + 256] = o1; yr[tid + 512] = o2;
    }
}

// ---------------- bf16 MFMA GEMM (m97 structure): C = act(A.B^T + bias) (+resid)
__global__ __launch_bounds__(256) void gemm_mfma(
    const ushort_t* __restrict__ A, const ushort_t* __restrict__ B,
    const float* __restrict__ bias, const float* __restrict__ resid,
    void* __restrict__ Cp, int K, int ldc, int ncol0, int act, int c_bf16)
{
    __shared__ ushort_t As[4096];   // 128 rows x 32 cols, 64 B/row, XOR-swizzled
    __shared__ ushort_t Bs[4096];
    int tid = threadIdx.x;
    int l = tid & 63, w = tid >> 6;
    int wr = w >> 1, wc = w & 1;
    int m0 = blockIdx.y * 128, n0 = blockIdx.x * 128;

    int srow[2], scol[2];
#pragma unroll
    for (int it = 0; it < 2; ++it) {
        int o = w * 1024 + it * 4096 + l * 16;
        int row = o >> 6;
        int sw = (o >> 4) & 3;
        srow[it] = row;
        scol[it] = (sw ^ ((row >> 1) & 3)) * 8;
    }
    const ushort_t* Abase = A + (size_t)m0 * K;
    const ushort_t* Bbase = B + (size_t)n0 * K;

    int kc = l >> 4, mr = l & 15;
    int aoff[4], boff[4];
#pragma unroll
    for (int i = 0; i < 4; ++i) {
        int r = wr * 64 + i * 16 + mr;
        aoff[i] = r * 64 + ((kc ^ ((r >> 1) & 3)) << 4);
        r = wc * 64 + i * 16 + mr;
        boff[i] = r * 64 + ((kc ^ ((r >> 1) & 3)) << 4);
    }

    f32x4 acc[4][4];
#pragma unroll
    for (int i = 0; i < 4; ++i)
#pragma unroll
        for (int j = 0; j < 4; ++j)
            acc[i][j] = (f32x4){0.f, 0.f, 0.f, 0.f};

    for (int k0 = 0; k0 < K; k0 += 32) {
        __syncthreads();
#pragma unroll
        for (int it = 0; it < 2; ++it) {
            GLD_LDS16(Abase + (size_t)srow[it] * K + k0 + scol[it],
                      (char*)As + w * 1024 + it * 4096);
            GLD_LDS16(Bbase + (size_t)srow[it] * K + k0 + scol[it],
                      (char*)Bs + w * 1024 + it * 4096);
        }
        __syncthreads();
        short8 af[4], bfr[4];
#pragma unroll
        for (int i = 0; i < 4; ++i) {
            af[i]  = *(const short8*)((const char*)As + aoff[i]);
            bfr[i] = *(const short8*)((const char*)Bs + boff[i]);
        }
#pragma unroll
        for (int i = 0; i < 4; ++i)
#pragma unroll
            for (int j = 0; j < 4; ++j)
                acc[i][j] = __builtin_amdgcn_mfma_f32_16x16x32_bf16(af[i], bfr[j], acc[i][j], 0, 0, 0);
    }

    int lq = l >> 4;
#pragma unroll
    for (int i = 0; i < 4; ++i) {
#pragma unroll
        for (int r = 0; r < 4; ++r) {
            int m = m0 + wr * 64 + i * 16 + lq * 4 + r;
#pragma unroll
            for (int j = 0; j < 4; ++j) {
                int n = n0 + wc * 64 + j * 16 + mr;
                float v = acc[i][j][r];
                if (bias) v += bias[n];
                if (act) {
                    float u = v;
                    float t = 0.7978845608028654f * (u + 0.044715f * u * u * u);
                    v = 0.5f * u * (1.0f + tanhf(t));
                }
                size_t idx = (size_t)m * ldc + ncol0 + n;
                if (resid) v += resid[idx];
                if (c_bf16) ((ushort_t*)Cp)[idx] = f2bf(v);
                else        ((float*)Cp)[idx] = v;
            }
        }
    }
}

// ---------------- MFMA flash attention. Block = (64-q tile, head), 4 waves.
// Wave w owns q rows [w*16, w*16+16). qkv bf16 [SPAD, 2304]; att bf16 [SPAD, 768].
__global__ __launch_bounds__(256) void attn_mfma(
    const ushort_t* __restrict__ qkv, ushort_t* __restrict__ att)
{
    __shared__ ushort_t Qs[64][72];   // [q][d]   pad 72 -> frag reads 2-way banks (free)
    __shared__ ushort_t Ks[64][72];   // [key][d]
    __shared__ ushort_t Vt[64][72];   // [d][key]
    __shared__ ushort_t Ps[64][72];   // [q][key] wave-private rows

    int qt  = (int)gridDim.x - 1 - (int)blockIdx.x;   // heavy tiles first
    int h   = blockIdx.y;
    int tid = threadIdx.x;
    int w = tid >> 6, lane = tid & 63;
    int quad = lane >> 4, l16 = lane & 15;
    int sr = lane;   // staging: seq row
    int dg = w;      // staging: d-group (16 d's)

    // stage Q tile
    {
        const ushort_t* qp = qkv + (size_t)(qt * 64 + sr) * QKVLD + h * HDIM + dg * 16;
        *(short8*)&Qs[sr][dg * 16]     = *(const short8*)qp;
        *(short8*)&Qs[sr][dg * 16 + 8] = *(const short8*)(qp + 8);
    }
    __syncthreads();
    short8 qf[2];
    qf[0] = *(const short8*)&Qs[w * 16 + l16][quad * 8];
    qf[1] = *(const short8*)&Qs[w * 16 + l16][32 + quad * 8];

    float mstate[4] = {-1e30f, -1e30f, -1e30f, -1e30f};
    float lstate[4] = {0.f, 0.f, 0.f, 0.f};
    f32x4 accO[4];
#pragma unroll
    for (int j = 0; j < 4; ++j) accO[j] = (f32x4){0.f, 0.f, 0.f, 0.f};

    for (int kt = 0; kt <= qt; ++kt) {
        __syncthreads();   // all waves done reading Ks/Vt of prev iter
        {
            const ushort_t* kp = qkv + (size_t)(kt * 64 + sr) * QKVLD + DMODEL + h * HDIM + dg * 16;
            *(short8*)&Ks[sr][dg * 16]     = *(const short8*)kp;
            *(short8*)&Ks[sr][dg * 16 + 8] = *(const short8*)(kp + 8);
            const ushort_t* vp = qkv + (size_t)(kt * 64 + sr) * QKVLD + 2 * DMODEL + h * HDIM + dg * 16;
            short8 v0 = *(const short8*)vp;
            short8 v1 = *(const short8*)(vp + 8);
#pragma unroll
            for (int j = 0; j < 8; ++j) Vt[dg * 16 + j][sr] = (ushort_t)v0[j];
#pragma unroll
            for (int j = 0; j < 8; ++j) Vt[dg * 16 + 8 + j][sr] = (ushort_t)v1[j];
        }
        __syncthreads();

        // S = Q K^T : wave strip 16 x 64
        f32x4 sacc[4];
#pragma unroll
        for (int nt = 0; nt < 4; ++nt) {
            sacc[nt] = (f32x4){0.f, 0.f, 0.f, 0.f};
            short8 kf0 = *(const short8*)&Ks[nt * 16 + l16][quad * 8];
            short8 kf1 = *(const short8*)&Ks[nt * 16 + l16][32 + quad * 8];
            sacc[nt] = __builtin_amdgcn_mfma_f32_16x16x32_bf16(qf[0], kf0, sacc[nt], 0, 0, 0);
            sacc[nt] = __builtin_amdgcn_mfma_f32_16x16x32_bf16(qf[1], kf1, sacc[nt], 0, 0, 0);
        }

        // online softmax — all in registers; D row = quad*4+r, col = l16
        bool diag = (kt == qt);
        float s[4][4], rmax[4];
#pragma unroll
        for (int r = 0; r < 4; ++r) rmax[r] = -1e30f;
#pragma unroll
        for (int nt = 0; nt < 4; ++nt)
#pragma unroll
            for (int r = 0; r < 4; ++r) {
                float v = sacc[nt][r] * 0.125f;
                if (diag && (nt * 16 + l16) > (w * 16 + quad * 4 + r)) v = -1e30f;
                s[nt][r] = v;
                rmax[r] = fmaxf(rmax[r], v);
            }
#pragma unroll
        for (int r = 0; r < 4; ++r) {
            rmax[r] = fmaxf(rmax[r], __shfl_xor(rmax[r], 1));
            rmax[r] = fmaxf(rmax[r], __shfl_xor(rmax[r], 2));
            rmax[r] = fmaxf(rmax[r], __shfl_xor(rmax[r], 4));
            rmax[r] = fmaxf(rmax[r], __shfl_xor(rmax[r], 8));
        }
        float alpha[4];
#pragma unroll
        for (int r = 0; r < 4; ++r) {
            float mnew = fmaxf(mstate[r], rmax[r]);
            alpha[r] = __expf(mstate[r] - mnew);
            mstate[r] = mnew;
        }
        float rsum[4] = {0.f, 0.f, 0.f, 0.f};
#pragma unroll
        for (int nt = 0; nt < 4; ++nt)
#pragma unroll
            for (int r = 0; r < 4; ++r) {
                float p = __expf(s[nt][r] - mstate[r]);
                Ps[w * 16 + quad * 4 + r][nt * 16 + l16] = f2bf(p);
                rsum[r] += p;
            }
#pragma unroll
        for (int r = 0; r < 4; ++r) {
            rsum[r] += __shfl_xor(rsum[r], 1);
            rsum[r] += __shfl_xor(rsum[r], 2);
            rsum[r] += __shfl_xor(rsum[r], 4);
            rsum[r] += __shfl_xor(rsum[r], 8);
            lstate[r] = lstate[r] * alpha[r] + rsum[r];
        }
#pragma unroll
        for (int j = 0; j < 4; ++j)
#pragma unroll
            for (int r = 0; r < 4; ++r) accO[j][r] *= alpha[r];

        // O += P V  (Ps rows are wave-private; DS ops in-order within wave)
        short8 pf0 = *(const short8*)&Ps[w * 16 + l16][quad * 8];
        short8 pf1 = *(const short8*)&Ps[w * 16 + l16][32 + quad * 8];
#pragma unroll
        for (int j = 0; j < 4; ++j) {
            short8 vf0 = *(const short8*)&Vt[j * 16 + l16][quad * 8];
            short8 vf1 = *(const short8*)&Vt[j * 16 + l16][32 + quad * 8];
            accO[j] = __builtin_amdgcn_mfma_f32_16x16x32_bf16(pf0, vf0, accO[j], 0, 0, 0);
            accO[j] = __builtin_amdgcn_mfma_f32_16x16x32_bf16(pf1, vf1, accO[j], 0, 0, 0);
        }
    }

    // epilogue: O /= l, store bf16
#pragma unroll
    for (int j = 0; j < 4; ++j)
#pragma unroll
        for (int r = 0; r < 4; ++r) {
            float o = accO[j][r] / lstate[r];
            att[(size_t)(qt * 64 + w * 16 + quad * 4 + r) * DMODEL + h * HDIM + j * 16 + l16] = f2bf(o);
        }
}

extern "C" void kernel_launch(void* const* d_in, const int* in_sizes, int n_in,
                              void* d_out, int out_size, void* d_ws, size_t ws_size,
                              hipStream_t stream) {
    const int*   tokens = (const int*)d_in[0];
    const float* emb    = (const float*)d_in[1];
    const float* pos    = (const float*)d_in[2];
    const float* mem    = (const float*)d_in[3];
    const float* ln1_s  = (const float*)d_in[4];
    const float* ln1_b  = (const float*)d_in[5];
    const float* wq     = (const float*)d_in[6];
    const float* wk     = (const float*)d_in[7];
    const float* wv     = (const float*)d_in[8];
    const float* wo     = (const float*)d_in[9];
    const float* ln2_s  = (const float*)d_in[10];
    const float* ln2_b  = (const float*)d_in[11];
    const float* w1     = (const float*)d_in[12];
    const float* b1     = (const float*)d_in[13];
    const float* w2     = (const float*)d_in[14];
    const float* b2     = (const float*)d_in[15];
    const float* lnm_s  = (const float*)d_in[16];
    const float* lnm_b  = (const float*)d_in[17];
    float* out = (float*)d_out;

    const int D = DMODEL, L = 4, FF = 4 * DMODEL, SP = SPAD;
    const int DD = D * D;            // 589824
    const int DF = D * FF;           // 2359296

    float*    x    = (float*)d_ws;                        // SP*768 f32
    ushort_t* qkvb = (ushort_t*)(x + (size_t)SP * D);     // SP*2304 bf16
    ushort_t* nbuf = qkvb + (size_t)SP * 3 * D;           // SP*768 bf16
    ushort_t* attb = nbuf + (size_t)SP * D;               // SP*768 bf16
    ushort_t* ffh  = attb + (size_t)SP * D;               // SP*3072 bf16
    ushort_t* wqkv = ffh  + (size_t)SP * FF;              // 2304*768 bf16
    ushort_t* wob  = wqkv + (size_t)3 * DD;
    ushort_t* w1b  = wob  + (size_t)DD;
    ushort_t* w2b  = w1b  + (size_t)DF;

    embed_kernel<<<SP, 256, 0, stream>>>(tokens, emb, pos, mem, x);

    dim3 gQKV(18, 17);   // N=2304
    dim3 gO(6, 17);      // N=768
    dim3 gF1(24, 17);    // N=3072
    dim3 gA(S_TOT / 64, NHEAD);   // 33 x 12

    for (int l = 0; l < L; ++l) {
        cvt_kernel<<<DD / 1024, 256, 0, stream>>>(wq + (size_t)l * DD, wqkv, DD);
        cvt_kernel<<<DD / 1024, 256, 0, stream>>>(wk + (size_t)l * DD, wqkv + DD, DD);
        cvt_kernel<<<DD / 1024, 256, 0, stream>>>(wv + (size_t)l * DD, wqkv + 2 * DD, DD);
        cvt_kernel<<<DD / 1024, 256, 0, stream>>>(wo + (size_t)l * DD, wob, DD);
        cvt_kernel<<<DF / 1024, 256, 0, stream>>>(w1 + (size_t)l * DF, w1b, DF);
        cvt_kernel<<<DF / 1024, 256, 0, stream>>>(w2 + (size_t)l * DF, w2b, DF);

        ln_kernel<ushort_t><<<SP, 256, 0, stream>>>(x, ln1_s + l * D, ln1_b + l * D, nbuf);
        gemm_mfma<<<gQKV, 256, 0, stream>>>(nbuf, wqkv, nullptr, nullptr,
                                            qkvb, D, 3 * D, 0, 0, 1);
        attn_mfma<<<gA, 256, 0, stream>>>(qkvb, attb);
        gemm_mfma<<<gO, 256, 0, stream>>>(attb, wob, nullptr, x,
                                          x, D, D, 0, 0, 0);
        ln_kernel<ushort_t><<<SP, 256, 0, stream>>>(x, ln2_s + l * D, ln2_b + l * D, nbuf);
        gemm_mfma<<<gF1, 256, 0, stream>>>(nbuf, w1b, b1 + (size_t)l * FF, nullptr,
                                           ffh, D, FF, 0, 1, 1);
        gemm_mfma<<<gO, 256, 0, stream>>>(ffh, w2b, b2 + (size_t)l * D, x,
                                          x, FF, D, 0, 0, 0);
    }
    ln_kernel<float><<<NMEM, 256, 0, stream>>>(x + (size_t)(S_TOT - NMEM) * D,
                                               lnm_s, lnm_b, out);
}

// Round 5
// 1362.062 us; speedup vs baseline: 5.5776x; 1.0613x over previous
//
#include <hip/hip_runtime.h>
#include <math.h>

#define S_TOT 2112
#define SPAD  2176   // 17 * 128
#define DMODEL 768
#define QKVLD 2304
#define NMEM 64
#define NHEAD 12
#define HDIM 64

typedef unsigned short ushort_t;
typedef __attribute__((ext_vector_type(8))) short short8;
typedef __attribute__((ext_vector_type(4))) float f32x4;

__device__ __forceinline__ ushort_t f2bf(float f) {
    unsigned int u = __builtin_bit_cast(unsigned int, f);
    u = (u + 0x7FFFu + ((u >> 16) & 1u)) >> 16;   // RNE
    return (ushort_t)u;
}

// wait lgkmcnt(0) only — leave vmcnt/expcnt open so prefetch loads stay in flight
#define WAIT_LGKM() __builtin_amdgcn_s_waitcnt(0xC07F)
#define BAR()       __builtin_amdgcn_s_barrier()

// ---------------- f32 -> bf16 convert
__global__ __launch_bounds__(256) void cvt_kernel(
    const float* __restrict__ src, ushort_t* __restrict__ dst, int n)
{
    int i = (blockIdx.x * 256 + threadIdx.x) * 4;
    if (i < n) {
        float4 v = *(const float4*)(src + i);
        ushort4 o;
        o.x = f2bf(v.x); o.y = f2bf(v.y); o.z = f2bf(v.z); o.w = f2bf(v.w);
        *(ushort4*)(dst + i) = o;
    }
}

// ---------------- embedding (pads rows >= S_TOT with zeros)
__global__ __launch_bounds__(256) void embed_kernel(
    const int* __restrict__ tokens, const float* __restrict__ emb,
    const float* __restrict__ pos, const float* __restrict__ mem,
    float* __restrict__ x)
{
    int s = blockIdx.x;
    int tid = threadIdx.x;
    float* xr = x + (size_t)s * DMODEL;
    if (s >= S_TOT) {
        for (int d = tid; d < DMODEL; d += 256) xr[d] = 0.0f;
    } else if (s < NMEM) {
        const float* mr = mem + (size_t)s * DMODEL;
        for (int d = tid; d < DMODEL; d += 256) xr[d] = mr[d];
    } else {
        int t = s - NMEM;
        int tok = tokens[t];
        const float* er = emb + (size_t)tok * DMODEL;
        const float* pr = pos + (size_t)t * DMODEL;
        for (int d = tid; d < DMODEL; d += 256) xr[d] = er[d] + pr[d];
    }
}

// ---------------- layernorm
template <typename OUT>
__global__ __launch_bounds__(256) void ln_kernel(
    const float* __restrict__ X, const float* __restrict__ g,
    const float* __restrict__ b, OUT* __restrict__ Y)
{
    __shared__ float red[256];
    int row = blockIdx.x, tid = threadIdx.x;
    const float* xr = X + (size_t)row * DMODEL;
    float v0 = xr[tid], v1 = xr[tid + 256], v2 = xr[tid + 512];
    red[tid] = v0 + v1 + v2;
    __syncthreads();
    for (int s = 128; s > 0; s >>= 1) {
        if (tid < s) red[tid] += red[tid + s];
        __syncthreads();
    }
    float mu = red[0] * (1.0f / 768.0f);
    __syncthreads();
    float d0 = v0 - mu, d1 = v1 - mu, d2 = v2 - mu;
    red[tid] = d0 * d0 + d1 * d1 + d2 * d2;
    __syncthreads();
    for (int s = 128; s > 0; s >>= 1) {
        if (tid < s) red[tid] += red[tid + s];
        __syncthreads();
    }
    float inv = rsqrtf(red[0] * (1.0f / 768.0f) + 1e-5f);
    OUT* yr = Y + (size_t)row * DMODEL;
    float o0 = d0 * inv * g[tid]       + b[tid];
    float o1 = d1 * inv * g[tid + 256] + b[tid + 256];
    float o2 = d2 * inv * g[tid + 512] + b[tid + 512];
    if constexpr (sizeof(OUT) == 2) {
        yr[tid] = f2bf(o0); yr[tid + 256] = f2bf(o1); yr[tid + 512] = f2bf(o2);
    } else {
        yr[tid] = o0; yr[tid + 256] = o1; yr[tid + 512] = o2;
    }
}

// ---------------- bf16 MFMA GEMM, register-prefetch double-buffered pipeline.
// C = act(A.B^T + bias) (+resid). A:[M,K] B:[N,K] bf16 row-major. 128x128 tile,
// BK=32, one lgkm-only barrier per K-step; global prefetch stays in flight
// across the barrier (no vmcnt(0) drain in the loop).
__global__ __launch_bounds__(256) void gemm_mfma(
    const ushort_t* __restrict__ A, const ushort_t* __restrict__ B,
    const float* __restrict__ bias, const float* __restrict__ resid,
    void* __restrict__ Cp, int K, int ldc, int ncol0, int act, int c_bf16)
{
    __shared__ ushort_t As[2][4096];   // 128 rows x 32, 64 B/row, XOR-swizzled
    __shared__ ushort_t Bs[2][4096];
    int tid = threadIdx.x;
    int l = tid & 63, w = tid >> 6;
    int wr = w >> 1, wc = w & 1;
    int m0 = blockIdx.y * 128, n0 = blockIdx.x * 128;

    // staging: per wave 2 row-groups of 16 rows; lane covers k-chunk g (16 B)
    int g = l & 3;
    int srow[2], swoff[2];
#pragma unroll
    for (int it = 0; it < 2; ++it) {
        int row = w * 32 + it * 16 + (l >> 2);
        srow[it] = row;
        swoff[it] = row * 64 + ((g ^ ((row >> 1) & 3)) << 4);   // byte offset
    }
    const ushort_t* Ap0 = A + (size_t)(m0 + srow[0]) * K + g * 8;
    const ushort_t* Ap1 = A + (size_t)(m0 + srow[1]) * K + g * 8;
    const ushort_t* Bp0 = B + (size_t)(n0 + srow[0]) * K + g * 8;
    const ushort_t* Bp1 = B + (size_t)(n0 + srow[1]) * K + g * 8;

    // fragment LDS byte offsets (verified layout)
    int kc = l >> 4, mr = l & 15;
    int aoff[4], boff[4];
#pragma unroll
    for (int i = 0; i < 4; ++i) {
        int r = wr * 64 + i * 16 + mr;
        aoff[i] = r * 64 + ((kc ^ ((r >> 1) & 3)) << 4);
        r = wc * 64 + i * 16 + mr;
        boff[i] = r * 64 + ((kc ^ ((r >> 1) & 3)) << 4);
    }

    f32x4 acc[4][4];
#pragma unroll
    for (int i = 0; i < 4; ++i)
#pragma unroll
        for (int j = 0; j < 4; ++j)
            acc[i][j] = (f32x4){0.f, 0.f, 0.f, 0.f};

    int nk = K >> 5;
    // prologue: tile0 -> buf0; tile1 -> regs (left in flight)
    short8 pa0 = *(const short8*)Ap0;
    short8 pa1 = *(const short8*)Ap1;
    short8 pb0 = *(const short8*)Bp0;
    short8 pb1 = *(const short8*)Bp1;
    *(short8*)((char*)As[0] + swoff[0]) = pa0;
    *(short8*)((char*)As[0] + swoff[1]) = pa1;
    *(short8*)((char*)Bs[0] + swoff[0]) = pb0;
    *(short8*)((char*)Bs[0] + swoff[1]) = pb1;
    pa0 = *(const short8*)(Ap0 + 32);
    pa1 = *(const short8*)(Ap1 + 32);
    pb0 = *(const short8*)(Bp0 + 32);
    pb1 = *(const short8*)(Bp1 + 32);
    WAIT_LGKM(); BAR();

    for (int k = 0; k < nk; ++k) {
        const char* bA = (const char*)As[k & 1];
        const char* bB = (const char*)Bs[k & 1];
        short8 af[4], bfr[4];
#pragma unroll
        for (int i = 0; i < 4; ++i) {
            af[i]  = *(const short8*)(bA + aoff[i]);
            bfr[i] = *(const short8*)(bB + boff[i]);
        }
#pragma unroll
        for (int i = 0; i < 4; ++i)
#pragma unroll
            for (int j = 0; j < 4; ++j)
                acc[i][j] = __builtin_amdgcn_mfma_f32_16x16x32_bf16(af[i], bfr[j], acc[i][j], 0, 0, 0);

        if (k + 1 < nk) {
            // commit prefetched tile k+1 (vmcnt wait is precise, auto-inserted)
            char* wA = (char*)As[(k + 1) & 1];
            char* wB = (char*)Bs[(k + 1) & 1];
            *(short8*)(wA + swoff[0]) = pa0;
            *(short8*)(wA + swoff[1]) = pa1;
            *(short8*)(wB + swoff[0]) = pb0;
            *(short8*)(wB + swoff[1]) = pb1;
            if (k + 2 < nk) {
                int ko = (k + 2) << 5;
                pa0 = *(const short8*)(Ap0 + ko);
                pa1 = *(const short8*)(Ap1 + ko);
                pb0 = *(const short8*)(Bp0 + ko);
                pb1 = *(const short8*)(Bp1 + ko);
            }
        }
        WAIT_LGKM(); BAR();
    }

    // epilogue: D row = (l>>4)*4 + reg, col = l&15 (m89-verified)
    int lq = l >> 4;
#pragma unroll
    for (int i = 0; i < 4; ++i) {
#pragma unroll
        for (int r = 0; r < 4; ++r) {
            int m = m0 + wr * 64 + i * 16 + lq * 4 + r;
#pragma unroll
            for (int j = 0; j < 4; ++j) {
                int n = n0 + wc * 64 + j * 16 + mr;
                float v = acc[i][j][r];
                if (bias) v += bias[n];
                if (act) {
                    float u = v;
                    float t = 0.7978845608028654f * (u + 0.044715f * u * u * u);
                    v = 0.5f * u * (1.0f + tanhf(t));
                }
                size_t idx = (size_t)m * ldc + ncol0 + n;
                if (resid) v += resid[idx];
                if (c_bf16) ((ushort_t*)Cp)[idx] = f2bf(v);
                else        ((float*)Cp)[idx] = v;
            }
        }
    }
}

// ---------------- MFMA flash attention. Block = (64-q tile, head), 4 waves.
__global__ __launch_bounds__(256) void attn_mfma(
    const ushort_t* __restrict__ qkv, ushort_t* __restrict__ att)
{
    __shared__ ushort_t Qs[64][72];
    __shared__ ushort_t Ks[64][72];
    __shared__ ushort_t Vt[64][72];
    __shared__ ushort_t Ps[64][72];

    int qt  = (int)gridDim.x - 1 - (int)blockIdx.x;
    int h   = blockIdx.y;
    int tid = threadIdx.x;
    int w = tid >> 6, lane = tid & 63;
    int quad = lane >> 4, l16 = lane & 15;
    int sr = lane;
    int dg = w;

    {
        const ushort_t* qp = qkv + (size_t)(qt * 64 + sr) * QKVLD + h * HDIM + dg * 16;
        *(short8*)&Qs[sr][dg * 16]     = *(const short8*)qp;
        *(short8*)&Qs[sr][dg * 16 + 8] = *(const short8*)(qp + 8);
    }
    __syncthreads();
    short8 qf[2];
    qf[0] = *(const short8*)&Qs[w * 16 + l16][quad * 8];
    qf[1] = *(const short8*)&Qs[w * 16 + l16][32 + quad * 8];

    float mstate[4] = {-1e30f, -1e30f, -1e30f, -1e30f};
    float lstate[4] = {0.f, 0.f, 0.f, 0.f};
    f32x4 accO[4];
#pragma unroll
    for (int j = 0; j < 4; ++j) accO[j] = (f32x4){0.f, 0.f, 0.f, 0.f};

    for (int kt = 0; kt <= qt; ++kt) {
        __syncthreads();
        {
            const ushort_t* kp = qkv + (size_t)(kt * 64 + sr) * QKVLD + DMODEL + h * HDIM + dg * 16;
            *(short8*)&Ks[sr][dg * 16]     = *(const short8*)kp;
            *(short8*)&Ks[sr][dg * 16 + 8] = *(const short8*)(kp + 8);
            const ushort_t* vp = qkv + (size_t)(kt * 64 + sr) * QKVLD + 2 * DMODEL + h * HDIM + dg * 16;
            short8 v0 = *(const short8*)vp;
            short8 v1 = *(const short8*)(vp + 8);
#pragma unroll
            for (int j = 0; j < 8; ++j) Vt[dg * 16 + j][sr] = (ushort_t)v0[j];
#pragma unroll
            for (int j = 0; j < 8; ++j) Vt[dg * 16 + 8 + j][sr] = (ushort_t)v1[j];
        }
        __syncthreads();

        f32x4 sacc[4];
#pragma unroll
        for (int nt = 0; nt < 4; ++nt) {
            sacc[nt] = (f32x4){0.f, 0.f, 0.f, 0.f};
            short8 kf0 = *(const short8*)&Ks[nt * 16 + l16][quad * 8];
            short8 kf1 = *(const short8*)&Ks[nt * 16 + l16][32 + quad * 8];
            sacc[nt] = __builtin_amdgcn_mfma_f32_16x16x32_bf16(qf[0], kf0, sacc[nt], 0, 0, 0);
            sacc[nt] = __builtin_amdgcn_mfma_f32_16x16x32_bf16(qf[1], kf1, sacc[nt], 0, 0, 0);
        }

        bool diag = (kt == qt);
        float s[4][4], rmax[4];
#pragma unroll
        for (int r = 0; r < 4; ++r) rmax[r] = -1e30f;
#pragma unroll
        for (int nt = 0; nt < 4; ++nt)
#pragma unroll
            for (int r = 0; r < 4; ++r) {
                float v = sacc[nt][r] * 0.125f;
                if (diag && (nt * 16 + l16) > (w * 16 + quad * 4 + r)) v = -1e30f;
                s[nt][r] = v;
                rmax[r] = fmaxf(rmax[r], v);
            }
#pragma unroll
        for (int r = 0; r < 4; ++r) {
            rmax[r] = fmaxf(rmax[r], __shfl_xor(rmax[r], 1));
            rmax[r] = fmaxf(rmax[r], __shfl_xor(rmax[r], 2));
            rmax[r] = fmaxf(rmax[r], __shfl_xor(rmax[r], 4));
            rmax[r] = fmaxf(rmax[r], __shfl_xor(rmax[r], 8));
        }
        float alpha[4];
#pragma unroll
        for (int r = 0; r < 4; ++r) {
            float mnew = fmaxf(mstate[r], rmax[r]);
            alpha[r] = __expf(mstate[r] - mnew);
            mstate[r] = mnew;
        }
        float rsum[4] = {0.f, 0.f, 0.f, 0.f};
#pragma unroll
        for (int nt = 0; nt < 4; ++nt)
#pragma unroll
            for (int r = 0; r < 4; ++r) {
                float p = __expf(s[nt][r] - mstate[r]);
                Ps[w * 16 + quad * 4 + r][nt * 16 + l16] = f2bf(p);
                rsum[r] += p;
            }
#pragma unroll
        for (int r = 0; r < 4; ++r) {
            rsum[r] += __shfl_xor(rsum[r], 1);
            rsum[r] += __shfl_xor(rsum[r], 2);
            rsum[r] += __shfl_xor(rsum[r], 4);
            rsum[r] += __shfl_xor(rsum[r], 8);
            lstate[r] = lstate[r] * alpha[r] + rsum[r];
        }
#pragma unroll
        for (int j = 0; j < 4; ++j)
#pragma unroll
            for (int r = 0; r < 4; ++r) accO[j][r] *= alpha[r];

        short8 pf0 = *(const short8*)&Ps[w * 16 + l16][quad * 8];
        short8 pf1 = *(const short8*)&Ps[w * 16 + l16][32 + quad * 8];
#pragma unroll
        for (int j = 0; j < 4; ++j) {
            short8 vf0 = *(const short8*)&Vt[j * 16 + l16][quad * 8];
            short8 vf1 = *(const short8*)&Vt[j * 16 + l16][32 + quad * 8];
            accO[j] = __builtin_amdgcn_mfma_f32_16x16x32_bf16(pf0, vf0, accO[j], 0, 0, 0);
            accO[j] = __builtin_amdgcn_mfma_f32_16x16x32_bf16(pf1, vf1, accO[j], 0, 0, 0);
        }
    }

#pragma unroll
    for (int j = 0; j < 4; ++j)
#pragma unroll
        for (int r = 0; r < 4; ++r) {
            float o = accO[j][r] / lstate[r];
            att[(size_t)(qt * 64 + w * 16 + quad * 4 + r) * DMODEL + h * HDIM + j * 16 + l16] = f2bf(o);
        }
}

extern "C" void kernel_launch(void* const* d_in, const int* in_sizes, int n_in,
                              void* d_out, int out_size, void* d_ws, size_t ws_size,
                              hipStream_t stream) {
    const int*   tokens = (const int*)d_in[0];
    const float* emb    = (const float*)d_in[1];
    const float* pos    = (const float*)d_in[2];
    const float* mem    = (const float*)d_in[3];
    const float* ln1_s  = (const float*)d_in[4];
    const float* ln1_b  = (const float*)d_in[5];
    const float* wq     = (const float*)d_in[6];
    const float* wk     = (const float*)d_in[7];
    const float* wv     = (const float*)d_in[8];
    const float* wo     = (const float*)d_in[9];
    const float* ln2_s  = (const float*)d_in[10];
    const float* ln2_b  = (const float*)d_in[11];
    const float* w1     = (const float*)d_in[12];
    const float* b1     = (const float*)d_in[13];
    const float* w2     = (const float*)d_in[14];
    const float* b2     = (const float*)d_in[15];
    const float* lnm_s  = (const float*)d_in[16];
    const float* lnm_b  = (const float*)d_in[17];
    float* out = (float*)d_out;

    const int D = DMODEL, L = 4, FF = 4 * DMODEL, SP = SPAD;
    const int DD = D * D;
    const int DF = D * FF;

    float*    x    = (float*)d_ws;
    ushort_t* qkvb = (ushort_t*)(x + (size_t)SP * D);
    ushort_t* nbuf = qkvb + (size_t)SP * 3 * D;
    ushort_t* attb = nbuf + (size_t)SP * D;
    ushort_t* ffh  = attb + (size_t)SP * D;
    ushort_t* wqkv = ffh  + (size_t)SP * FF;
    ushort_t* wob  = wqkv + (size_t)3 * DD;
    ushort_t* w1b  = wob  + (size_t)DD;
    ushort_t* w2b  = w1b  + (size_t)DF;

    embed_kernel<<<SP, 256, 0, stream>>>(tokens, emb, pos, mem, x);

    dim3 gQKV(18, 17);   // N=2304
    dim3 gO(6, 17);      // N=768
    dim3 gF1(24, 17);    // N=3072
    dim3 gA(S_TOT / 64, NHEAD);

    for (int l = 0; l < L; ++l) {
        cvt_kernel<<<DD / 1024, 256, 0, stream>>>(wq + (size_t)l * DD, wqkv, DD);
        cvt_kernel<<<DD / 1024, 256, 0, stream>>>(wk + (size_t)l * DD, wqkv + DD, DD);
        cvt_kernel<<<DD / 1024, 256, 0, stream>>>(wv + (size_t)l * DD, wqkv + 2 * DD, DD);
        cvt_kernel<<<DD / 1024, 256, 0, stream>>>(wo + (size_t)l * DD, wob, DD);
        cvt_kernel<<<DF / 1024, 256, 0, stream>>>(w1 + (size_t)l * DF, w1b, DF);
        cvt_kernel<<<DF / 1024, 256, 0, stream>>>(w2 + (size_t)l * DF, w2b, DF);

        ln_kernel<ushort_t><<<SP, 256, 0, stream>>>(x, ln1_s + l * D, ln1_b + l * D, nbuf);
        gemm_mfma<<<gQKV, 256, 0, stream>>>(nbuf, wqkv, nullptr, nullptr,
                                            qkvb, D, 3 * D, 0, 0, 1);
        attn_mfma<<<gA, 256, 0, stream>>>(qkvb, attb);
        gemm_mfma<<<gO, 256, 0, stream>>>(attb, wob, nullptr, x,
                                          x, D, D, 0, 0, 0);
        ln_kernel<ushort_t><<<SP, 256, 0, stream>>>(x, ln2_s + l * D, ln2_b + l * D, nbuf);
        gemm_mfma<<<gF1, 256, 0, stream>>>(nbuf, w1b, b1 + (size_t)l * FF, nullptr,
                                           ffh, D, FF, 0, 1, 1);
        gemm_mfma<<<gO, 256, 0, stream>>>(ffh, w2b, b2 + (size_t)l * D, x,
                                          x, FF, D, 0, 0, 0);
    }
    ln_kernel<float><<<NMEM, 256, 0, stream>>>(x + (size_t)(S_TOT - NMEM) * D,
                                               lnm_s, lnm_b, out);
}